// Round 9
// baseline (105.223 us; speedup 1.0000x reference)
//
#include <hip/hip_runtime.h>
#include <hip/hip_bf16.h>
#include <stdint.h>

// Problem constants
#define E_    8
#define K_    2048
#define N_    2048
#define T_    1024
#define TOPK_ 2
#define NG_   16      // K/GROUP_SIZE
#define MAXM  512     // per-expert pair capacity (mean 256, sd~15 -> +17 sigma)

// GEMM tile
#define BM 128
#define BN 64
#define BK 64
#define NST (K_ / BK)        // 32 K-steps
#define MTILES (MAXM / BM)   // 4
#define BSTRIDE 68           // padded B-row stride in u16 (136 B = 34 banks)

typedef __attribute__((ext_vector_type(8))) short bf16x8;
typedef __attribute__((ext_vector_type(4))) float f32x4;
typedef __attribute__((ext_vector_type(4))) int i32x4;
typedef __attribute__((ext_vector_type(2))) unsigned int u32x2;
typedef __attribute__((ext_vector_type(4))) unsigned int u32x4;
typedef __attribute__((ext_vector_type(8))) unsigned short u16x8;

__device__ __forceinline__ unsigned short f2bf_rne(float f) {
    unsigned u = __float_as_uint(f);
    u += 0x7fffu + ((u >> 16) & 1u);
    return (unsigned short)(u >> 16);
}
// exact pack for ints 0..255 (<=8 significand bits -> bf16 exact)
__device__ __forceinline__ unsigned pack2bf(int lo, int hi) {
    float fl = (float)lo, fh = (float)hi;
    return (__float_as_uint(fl) >> 16) | (__float_as_uint(fh) & 0xffff0000u);
}

// ---------------- kernel 1: extract diagonal scales/zeros, zero counters ----
__global__ void prep_sz(const float* __restrict__ scales, const float* __restrict__ zeros,
                        float* __restrict__ sd, float* __restrict__ zd, int* __restrict__ cnt)
{
    int i = blockIdx.x * 256 + threadIdx.x;      // over E*K = 16384
    int e = i >> 11;
    int k = i & (K_ - 1);
    int g = k >> 7;
    size_t src = ((size_t)e * K_ + k) * NG_ + g;
    sd[i] = scales[src];
    zd[i] = zeros[src];
    if (i < E_) cnt[i] = 0;
}

// ---------------- kernel 2: route pairs (t,j) -> per-expert compact lists ---
__global__ void route_k(const int* __restrict__ topk_ids, int* __restrict__ cnt,
                        int* __restrict__ ptj)
{
    int idx = blockIdx.x * 256 + threadIdx.x;    // grid 8 x 256 = 2048
    if (idx < T_ * TOPK_) {
        int e = topk_ids[idx];
        int slot = atomicAdd(&cnt[e], 1);
        if (slot < T_ * TOPK_) ptj[e * (T_ * TOPK_) + slot] = idx;
    }
}

// ---------------- kernel 3: zdot[t*2+j] = dot(x[t], z_diag[e]) --------------
__global__ void zdot_k(const float* __restrict__ x, const float* __restrict__ zdiag,
                       const int* __restrict__ topk_ids, float* __restrict__ zdot)
{
    int w = (int)((blockIdx.x * blockDim.x + threadIdx.x) >> 6);  // pair index
    int lane = threadIdx.x & 63;
    int t = w >> 1;
    int e = topk_ids[w];
    const f32x4* xp = (const f32x4*)(x + (size_t)t * K_);
    const f32x4* zp = (const f32x4*)(zdiag + (size_t)e * K_);
    float acc = 0.f;
#pragma unroll
    for (int it = 0; it < K_ / 256; ++it) {
        f32x4 a = xp[it * 64 + lane];
        f32x4 b = zp[it * 64 + lane];
        acc += a.x * b.x + a.y * b.y + a.z * b.z + a.w * b.w;
    }
#pragma unroll
    for (int off = 32; off > 0; off >>= 1) acc += __shfl_xor(acc, off);
    if (lane == 0) zdot[w] = acc;
}

// ---------------- kernel 4: pack A[e][slot][k] = bf16(x[t,k]*s[e,k]) --------
__global__ void aprep_k(const float* __restrict__ x, const float* __restrict__ sdiag,
                        const int* __restrict__ cnt, const int* __restrict__ ptj,
                        unsigned short* __restrict__ apack)
{
    int e = blockIdx.y;
    int slot = blockIdx.x;
    if (slot >= min(cnt[e], MAXM)) return;
    int tj = ptj[e * (T_ * TOPK_) + slot];
    int t = tj >> 1;
    const float* xr = x + (size_t)t * K_;
    const float* sr = sdiag + (size_t)e * K_;
    int k = threadIdx.x * 8;
    f32x4 a0 = *(const f32x4*)(xr + k);
    f32x4 s0 = *(const f32x4*)(sr + k);
    f32x4 a1 = *(const f32x4*)(xr + k + 4);
    f32x4 s1 = *(const f32x4*)(sr + k + 4);
    u16x8 h;
    h[0] = f2bf_rne(a0.x * s0.x);
    h[1] = f2bf_rne(a0.y * s0.y);
    h[2] = f2bf_rne(a0.z * s0.z);
    h[3] = f2bf_rne(a0.w * s0.w);
    h[4] = f2bf_rne(a1.x * s1.x);
    h[5] = f2bf_rne(a1.y * s1.y);
    h[6] = f2bf_rne(a1.z * s1.z);
    h[7] = f2bf_rne(a1.w * s1.w);
    *(u16x8*)(apack + ((size_t)e * MAXM + slot) * K_ + k) = h;
}

// ---------------- kernel 5: per-expert GEMM ---------------------------------
// 128x64 tile, BK=64. TA-LEAN B PATH: per step each thread issues 4 dwordx4
// ROW-wise reads of wq (4-lane 64B contiguous runs; 8 vmem instr/wave-step
// total vs 20 before). B transposed through a padded [64][68] u16 LDS tile
// (stride 136B): writes = 4x ds_write_b64; MFMA B-frags = 8x ds_read_u16 at
// immediate offsets + OR-pack. A path / schedule / epilogue = proven R8 code.
__global__ __launch_bounds__(256, 3)
void moe_gemm(const int* __restrict__ wq, const unsigned short* __restrict__ apack,
              const float* __restrict__ topk_w, const int* __restrict__ cnt,
              const int* __restrict__ ptj, const float* __restrict__ zdot,
              float* __restrict__ part, float* __restrict__ out, int use_part)
{
    int e = blockIdx.z;
    int count = min(cnt[e], MAXM);
    int m0 = blockIdx.y * BM;
    if (m0 >= count) return;                      // block-uniform early exit
    int n0 = blockIdx.x * BN;

    __shared__ alignas(16) unsigned short As[2][BM * BK];        // 2 x 16 KB
    __shared__ alignas(16) unsigned short Bs[2][BK * BSTRIDE];   // 2 x 8.5 KB

    int tid = threadIdx.x;
    int lane = tid & 63;
    int wid = tid >> 6;
    int wm = (wid >> 1) * 64;                     // wave tile 64m x 32n
    int wn = (wid & 1) * 32;

    // A reg-staging geometry: thread -> (row = tid>>3 (+32/round), slot = tid&7)
    int arow = tid >> 3;                          // 0..31
    int asl = tid & 7;
    const char* ag = (const char*)(apack + (size_t)e * MAXM * K_)
                   + ((size_t)(m0 + arow) * K_) * 2 + asl * 16;
    int alds = arow * 128 + ((asl ^ (arow & 7)) << 4);   // + r*4096 per round

    // B staging: thread -> (k-row = tid>>2, n-slot = (tid&3)*4; 4 instrs of
    // dwordx4 at n-slot + i*16) -> 4-lane 64 B contiguous runs per instr.
    int b_k = tid >> 2;                           // 0..63
    int b_ns = (tid & 3) * 4;                     // 0,4,8,12
    const int* brow = wq + (size_t)e * K_ * N_ + (size_t)b_k * N_ + n0 + b_ns;

    f32x4 acc[4][2] = {};
    i32x4 a0[4], a1[4];                           // 2 A reg sets
    i32x4 b0[4], b1[4], b2[4];                    // 3 B reg sets (4 dwordx4 each)

    auto loadA = [&](i32x4* dst, int kt) {
        const char* base = ag + (size_t)kt * (BK * 2);
#pragma unroll
        for (int r = 0; r < 4; ++r)
            dst[r] = *(const i32x4*)(base + (size_t)r * 32 * K_ * 2);
    };
    auto writeA = [&](const i32x4* src, int abuf) {
        char* l = (char*)As[abuf] + alds;
#pragma unroll
        for (int r = 0; r < 4; ++r)
            *(u32x4*)(l + r * 4096) = __builtin_bit_cast(u32x4, src[r]);
    };
    auto loadB = [&](i32x4* br, int kt) {
        const int* src = brow + (size_t)kt * BK * N_;
#pragma unroll
        for (int i = 0; i < 4; ++i)
            br[i] = *(const i32x4*)(src + i * 16);
    };
    auto writeB = [&](const i32x4* br, int bbuf) {
        unsigned short* rowp = &Bs[bbuf][b_k * BSTRIDE];
#pragma unroll
        for (int i = 0; i < 4; ++i) {
            i32x4 v = br[i];
            u32x2 h = { pack2bf(v.x, v.y), pack2bf(v.z, v.w) };
            *(u32x2*)(rowp + b_ns + i * 16) = h;   // 8 B, aligned (b_ns*2+i*32)
        }
    };
    auto comp = [&](int buf) {
#pragma unroll
        for (int kk2 = 0; kk2 < 2; ++kk2) {
            int kbyte = kk2 * 64 + ((lane >> 4) << 4);     // A frag k-byte
            int kb = kk2 * 32 + ((lane >> 4) << 3);        // B frag k-index
            bf16x8 af[4], bfr[2];
#pragma unroll
            for (int mi = 0; mi < 4; ++mi) {
                int row = wm + mi * 16 + (lane & 15);
                af[mi] = *(const bf16x8*)((const char*)As[buf] + row * 128 + (kbyte ^ ((row & 7) << 4)));
            }
#pragma unroll
            for (int ni = 0; ni < 2; ++ni) {
                int ncol = wn + ni * 16 + (lane & 15);
                const unsigned short* bp = &Bs[buf][kb * BSTRIDE + ncol];
                unsigned d0 = (unsigned)bp[0]           | ((unsigned)bp[BSTRIDE]     << 16);
                unsigned d1 = (unsigned)bp[2 * BSTRIDE] | ((unsigned)bp[3 * BSTRIDE] << 16);
                unsigned d2 = (unsigned)bp[4 * BSTRIDE] | ((unsigned)bp[5 * BSTRIDE] << 16);
                unsigned d3 = (unsigned)bp[6 * BSTRIDE] | ((unsigned)bp[7 * BSTRIDE] << 16);
                union { unsigned u[4]; bf16x8 v; } f = {{ d0, d1, d2, d3 }};
                bfr[ni] = f.v;
            }
#pragma unroll
            for (int mi = 0; mi < 4; ++mi)
#pragma unroll
                for (int ni = 0; ni < 2; ++ni)
                    acc[mi][ni] = __builtin_amdgcn_mfma_f32_16x16x32_bf16(
                        af[mi], bfr[ni], acc[mi][ni], 0, 0, 0);
        }
    };

    // ---- prologue: tiles 0,1 loaded to regs; tile 0 written to LDS ----
    loadA(a0, 0);
    loadA(a1, 1);
    loadB(b0, 0);
    loadB(b1, 1);
    loadB(b2, 2);
    writeA(a0, 0);                                 // counted wait on a0 only
    writeB(b0, 0);                                 // counted wait on b0 only
    asm volatile("s_waitcnt lgkmcnt(0)" ::: "memory");
    __builtin_amdgcn_s_barrier();
    asm volatile("" ::: "memory");

    // step s: load A(s+2)->a[s&1], B(s+3)->b[s%3]; comp tile s (bufs s&1);
    // write A(s+1)/B(s+1) into the other buffers. Named reg sets (static).
    int kt = 0;
#define STEP(AL, BL, CC, AW, BP) do {                                         \
        loadA(AL, kt + 2);                                                    \
        loadB(BL, min(kt + 3, NST - 1));                                      \
        comp(CC);                                                             \
        writeA(AW, CC ^ 1);                                                   \
        writeB(BP, CC ^ 1);                                                   \
        asm volatile("s_waitcnt lgkmcnt(0)" ::: "memory");                    \
        __builtin_amdgcn_s_barrier();                                         \
        asm volatile("" ::: "memory");                                        \
        ++kt;                                                                 \
    } while (0)

#pragma unroll 1
    for (int it = 0; it < 5; ++it) {              // steps 0..29, period 6
        STEP(a0, b0, 0, a1, b1);
        STEP(a1, b1, 1, a0, b2);
        STEP(a0, b2, 0, a1, b0);
        STEP(a1, b0, 1, a0, b1);
        STEP(a0, b1, 0, a1, b2);
        STEP(a1, b2, 1, a0, b0);
    }
#undef STEP
    // ---- step 30: comp tile 30; stage tile 31 (a1 / b1, loaded s=29/28) ----
    comp(0);
    writeA(a1, 1);
    writeB(b1, 1);
    asm volatile("s_waitcnt lgkmcnt(0)" ::: "memory");
    __builtin_amdgcn_s_barrier();
    asm volatile("" ::: "memory");
    // ---- step 31 ----
    comp(1);

    // ---- epilogue: part[tj][n] = w*(acc+zdot)  (or atomic fallback) ----
#pragma unroll
    for (int mi = 0; mi < 4; ++mi) {
        int prow = m0 + wm + mi * 16 + ((lane >> 4) << 2);
#pragma unroll
        for (int r = 0; r < 4; ++r) {
            int p = prow + r;
            if (p < count) {
                int tj = ptj[e * (T_ * TOPK_) + p];
                float w = topk_w[tj];
                float zdv = zdot[tj];
                float v0 = w * (acc[mi][0][r] + zdv);
                float v1 = w * (acc[mi][1][r] + zdv);
                if (use_part) {
                    float* pr = part + (size_t)tj * N_ + n0 + wn + (lane & 15);
                    pr[0]  = v0;
                    pr[16] = v1;
                } else {
                    float* orow = out + (size_t)(tj >> 1) * N_ + n0 + wn + (lane & 15);
                    atomicAdd(orow + 0,  v0);
                    atomicAdd(orow + 16, v1);
                }
            }
        }
    }
}

// ---------------- kernel 6: out[t] = part[2t] + part[2t+1] ------------------
__global__ void reduce_k(const float* __restrict__ part, float* __restrict__ out)
{
    int g = blockIdx.x * 256 + threadIdx.x;       // over T*N/4
    int t = g >> 9;                                // N/4 = 512 f32x4 per row
    int nc = g & 511;
    f32x4 a = ((const f32x4*)part)[((size_t)(t * 2) << 9) + nc];
    f32x4 b = ((const f32x4*)part)[((size_t)(t * 2 + 1) << 9) + nc];
    ((f32x4*)out)[g] = a + b;
}

// ---------------- launch -----------------------------------------------------
extern "C" void kernel_launch(void* const* d_in, const int* in_sizes, int n_in,
                              void* d_out, int out_size, void* d_ws, size_t ws_size,
                              hipStream_t stream)
{
    const float* x       = (const float*)d_in[0];
    const int*   wq      = (const int*)d_in[1];
    const float* scales  = (const float*)d_in[2];
    const float* zeros   = (const float*)d_in[3];
    const float* topk_w  = (const float*)d_in[4];
    const int*   topk_id = (const int*)d_in[5];
    float* out = (float*)d_out;

    char* ws = (char*)d_ws;
    float* sdiag = (float*)(ws + 0);                    //  64 KB
    float* zdiag = (float*)(ws + 65536);                //  64 KB
    int*   cnt   = (int*)(ws + 131072);                 //  4 KB
    int*   ptj   = (int*)(ws + 135168);                 //  64 KB
    float* zdot  = (float*)(ws + 200704);               //  8 KB
    unsigned short* apack = (unsigned short*)(ws + (1 << 20));   // 16 MB
    float* part  = (float*)(ws + ((size_t)17 << 20));            // 16.8 MB
    size_t need = ((size_t)17 << 20) + (size_t)T_ * TOPK_ * N_ * sizeof(float);
    int use_part = (ws_size >= need) ? 1 : 0;

    prep_sz<<<E_ * K_ / 256, 256, 0, stream>>>(scales, zeros, sdiag, zdiag, cnt);
    route_k<<<T_ * TOPK_ / 256, 256, 0, stream>>>(topk_id, cnt, ptj);
    zdot_k<<<T_ * TOPK_ / 4, 256, 0, stream>>>(x, zdiag, topk_id, zdot);
    aprep_k<<<dim3(MAXM, E_), 256, 0, stream>>>(x, sdiag, cnt, ptj, apack);
    if (!use_part)
        hipMemsetAsync(d_out, 0, (size_t)T_ * N_ * sizeof(float), stream);
    moe_gemm<<<dim3(N_ / BN, MTILES, E_), 256, 0, stream>>>(
        wq, apack, topk_w, cnt, ptj, zdot, part, out, use_part);
    if (use_part)
        reduce_k<<<T_ * N_ / 4 / 256, 256, 0, stream>>>(part, out);
}